// Round 16
// baseline (50.217 us; speedup 1.0000x reference)
//
#include <hip/hip_runtime.h>

// AdditiveAttention: B=2,H=8,Q=512,K=512,D=64
//   scores[b,h,q,k] = V_b + sum_d V_w[d]*tanh(q_proj[q,d] + k_proj[k,d])
//
// tanh(x) = 1 - 2/(1+e^{2x});  e^{2(qp+kp)} = eq*gk,
//   eq = exp2(C*qp), gk = exp2(C*kp), C = 2*log2(e)
// term_d = Vw[d]/A_d,  A_d = 1 + eq_d*gk_d;  score = (Vb+sumVw) - 2*sum term_d
// tree8: 1 v_rcp per 8 elements, 3.875 VALU/elem.
//
// CONVOY-FREE design (R15 post-mortem): barrier-synced waves all hit the
// same lgkmcnt(0) together -> SIMD idles full latency each group. R4 (per-qi
// s_load bursts, no barrier phase) was the only 71%-VALUBusy variant.
// Here: wave = (qset, d-half); lane = k. kreg[32] per lane (half k-row, low
// pressure -> no spill); e via per-qi uniform s_load bursts; NO LDS and NO
// barrier in the hot loop; partial-sum combine through LDS in the epilogue.

#define BHX 16
#define SEQ 512
#define DDIM 64

typedef float f4 __attribute__((ext_vector_type(4)));

// Both projections in one launch. blocks 0..255: query->eq, 256..511: keys->gk.
// (R12-proven, no pins.)
__global__ __launch_bounds__(256) void proj_kernel(
    const float* __restrict__ query, const float* __restrict__ keys,
    const float* __restrict__ Wa_w,  const float* __restrict__ Wa_b,
    const float* __restrict__ Ua_w,  const float* __restrict__ Ua_b,
    float* __restrict__ eq, float* __restrict__ gk)
{
  const int t = threadIdx.x, lane = t & 63, wave = t >> 6;
  const bool is_k = blockIdx.x >= 256;
  const float* __restrict__ X  = is_k ? keys : query;
  const float* __restrict__ W  = is_k ? Ua_w : Wa_w;
  const float* __restrict__ Bv = is_k ? Ua_b : Wa_b;
  float* __restrict__ out      = is_k ? gk : eq;
  const int row0 = (blockIdx.x & 255) * 32;

  float w[64];
  const float4* W4 = (const float4*)(W + lane * DDIM);
#pragma unroll
  for (int i = 0; i < 16; ++i) {
    float4 v = W4[i];
    w[4*i] = v.x; w[4*i+1] = v.y; w[4*i+2] = v.z; w[4*i+3] = v.w;
  }

  const float C = 2.885390081777926815f;          // 2*log2(e)
  const float b = Bv[lane];

#pragma unroll 1
  for (int i = 0; i < 8; ++i) {
    const int r   = row0 + wave * 8 + i;
    const int off = __builtin_amdgcn_readfirstlane(r * DDIM);
    const float* xr = X + off;                    // wave-uniform -> s_load
    float a0 = 0, a1 = 0, a2 = 0, a3 = 0;
#pragma unroll
    for (int e = 0; e < 64; e += 4) {
      a0 = __builtin_fmaf(xr[e],     w[e],     a0);
      a1 = __builtin_fmaf(xr[e + 1], w[e + 1], a1);
      a2 = __builtin_fmaf(xr[e + 2], w[e + 2], a2);
      a3 = __builtin_fmaf(xr[e + 3], w[e + 3], a3);
    }
    float p = ((a0 + a1) + (a2 + a3)) + b;
    out[(size_t)r * DDIM + lane] = __builtin_amdgcn_exp2f(C * p);
  }
}

// Grid (8,16,16)=2048 blocks. Block tile: 32 q x 64 k.
// wave = (qset, half): qset = wave>>1 (16 q rows), half = wave&1 (32 d's).
// lane = k. Hot loop: kreg[32] VGPR-resident, e via uniform s_loads, no LDS.
__global__ __launch_bounds__(256) void score_kernel(
    const float* __restrict__ eq,   // [BH*512][64]
    const float* __restrict__ gk,   // [BH*512][64]
    const float* __restrict__ Vw,   // [64]
    const float* __restrict__ Vb,   // [1]
    float* __restrict__ out)        // [BH,512,512]
{
  __shared__ float part[4][16][66]; // [wave][qi][k], 16.9 KB, +2 pad

  const int bh   = blockIdx.z;
  const int q0   = blockIdx.y * 32;
  const int k0   = blockIdx.x * 64;
  const int t    = threadIdx.x;
  const int lane = t & 63;          // k within tile
  const int wave = t >> 6;
  const int qset = wave >> 1;       // 0,1: q rows [16*qset, 16*qset+16)
  const int half = wave & 1;        // d in [32*half, 32*half+32)

  // ---- lane's half k-row: 32 floats, 8 f4 loads (L2-resident, no pins) ----
  float kreg[32];
  {
    const f4* kb = (const f4*)(gk + (size_t)(bh * SEQ + k0 + lane) * DDIM
                               + half * 32);
#pragma unroll
    for (int i = 0; i < 8; ++i) {
      const f4 v = kb[i];
      kreg[4*i] = v.x; kreg[4*i+1] = v.y; kreg[4*i+2] = v.z; kreg[4*i+3] = v.w;
    }
  }
  // uniform Vw half-slice (scalar pipe)
  float vw[32];
#pragma unroll
  for (int j = 0; j < 32; ++j) vw[j] = Vw[half * 32 + j];

  // acc0 = V_b + sum_d V_w[d]  (uniform scalar; needed in epilogue)
  float acc0 = Vb[0];
#pragma unroll
  for (int d = 0; d < 64; ++d) acc0 += Vw[d];

  const int qbase = __builtin_amdgcn_readfirstlane(
      (bh * SEQ + q0 + qset * 16) * DDIM + half * 32);

#pragma unroll
  for (int qi = 0; qi < 16; ++qi) {       // fully unrolled: static indexing
    const float* er = eq + qbase + qi * DDIM;   // uniform -> s_load burst
    float a = 0.f;
#pragma unroll
    for (int g = 0; g < 4; ++g) {         // d-groups of 8 within the half
      float A[8];
#pragma unroll
      for (int j = 0; j < 8; ++j)
        A[j] = __builtin_fmaf(er[8*g + j], kreg[8*g + j], 1.0f);
      // tree8: sum_j vw[j]/A[j] = num/P, 1 rcp
      const float* vg = vw + 8 * g;
      const float n01 = __builtin_fmaf(vg[1], A[0], vg[0] * A[1]);
      const float n23 = __builtin_fmaf(vg[3], A[2], vg[2] * A[3]);
      const float n45 = __builtin_fmaf(vg[5], A[4], vg[4] * A[5]);
      const float n67 = __builtin_fmaf(vg[7], A[6], vg[6] * A[7]);
      const float P01 = A[0] * A[1], P23 = A[2] * A[3];
      const float P45 = A[4] * A[5], P67 = A[6] * A[7];
      const float n0123 = __builtin_fmaf(n23, P01, n01 * P23);
      const float n4567 = __builtin_fmaf(n67, P45, n45 * P67);
      const float P0123 = P01 * P23, P4567 = P45 * P67;
      const float num = __builtin_fmaf(n4567, P0123, n0123 * P4567);
      const float P   = P0123 * P4567;    // product of 8 A's >= 1: safe
      a = __builtin_fmaf(num, __builtin_amdgcn_rcpf(P), a);
    }
    part[wave][qi][lane] = a;             // LDS write, no sync needed yet
  }

  __syncthreads();

  // ---- combine halves + fold, coalesced stores: 8 outputs/thread ----
  {
    const int qrow = t >> 3;              // 0..31
    const int kc   = (t & 7) * 8;         // 0,8,..,56
    const int qs   = qrow >> 4;
    const int qi   = qrow & 15;
    const float* p0 = &part[qs * 2][qi][kc];
    const float* p1 = &part[qs * 2 + 1][qi][kc];
    f4 v0, v1;
    v0.x = __builtin_fmaf(-2.f, p0[0] + p1[0], acc0);
    v0.y = __builtin_fmaf(-2.f, p0[1] + p1[1], acc0);
    v0.z = __builtin_fmaf(-2.f, p0[2] + p1[2], acc0);
    v0.w = __builtin_fmaf(-2.f, p0[3] + p1[3], acc0);
    v1.x = __builtin_fmaf(-2.f, p0[4] + p1[4], acc0);
    v1.y = __builtin_fmaf(-2.f, p0[5] + p1[5], acc0);
    v1.z = __builtin_fmaf(-2.f, p0[6] + p1[6], acc0);
    v1.w = __builtin_fmaf(-2.f, p0[7] + p1[7], acc0);
    float* dst = out + (size_t)(bh * SEQ + q0 + qrow) * SEQ + k0 + kc;
    *(f4*)(dst)     = v0;
    *(f4*)(dst + 4) = v1;
  }
}

extern "C" void kernel_launch(void* const* d_in, const int* in_sizes, int n_in,
                              void* d_out, int out_size, void* d_ws, size_t ws_size,
                              hipStream_t stream) {
  const float* query = (const float*)d_in[0];  // [2,8,512,64]
  const float* keys  = (const float*)d_in[1];  // [2,8,512,64]
  const float* Wa_w  = (const float*)d_in[2];  // [64,64]
  const float* Wa_b  = (const float*)d_in[3];  // [64]
  const float* Ua_w  = (const float*)d_in[4];  // [64,64]
  const float* Ua_b  = (const float*)d_in[5];  // [64]
  const float* V_w   = (const float*)d_in[6];  // [64]
  const float* V_b   = (const float*)d_in[7];  // [1]
  float* out = (float*)d_out;

  const int R = BHX * SEQ;                 // 8192 rows each side
  float* eqw = (float*)d_ws;               // 2 MiB
  float* gkw = eqw + (size_t)R * DDIM;     // 2 MiB

  proj_kernel<<<512, 256, 0, stream>>>(query, keys, Wa_w, Wa_b,
                                       Ua_w, Ua_b, eqw, gkw);

  dim3 grid(SEQ / 64, SEQ / 32, BHX);      // (8,16,16) = 2048 blocks
  score_kernel<<<grid, 256, 0, stream>>>(eqw, gkw, V_w, V_b, out);
}